// Round 1
// baseline (5180.930 us; speedup 1.0000x reference)
//
#include <hip/hip_runtime.h>
#include <math.h>

#define NN 1024
#define SS 32
#define MV 32

// ws layout (floats): h[32768] | m[32768] | u[32768] | v[32768]  = 512 KB total

__device__ __forceinline__ float sigmoidf_(float x) { return 1.0f / (1.0f + __expf(-x)); }

// ---------------------------------------------------------------------------
// k_init: h=0, m=0, u[i][mm]=b[i]*wbi[mm], v[j][mm]=b[j]*wbj[mm]+b1[mm]
// 32768 threads (row = t>>5, mm = t&31)
// ---------------------------------------------------------------------------
__global__ __launch_bounds__(256) void k_init(
    const float* __restrict__ b, const float* __restrict__ W1,
    const float* __restrict__ b1, float* __restrict__ h,
    float* __restrict__ mbuf, float* __restrict__ u, float* __restrict__ v)
{
    int t = blockIdx.x * 256 + threadIdx.x;   // 0..32767
    int row = t >> 5;
    int mm  = t & 31;
    float bi = b[row];
    h[t]    = 0.0f;
    mbuf[t] = 0.0f;
    u[t] = bi * W1[mm * 67 + 65];
    v[t] = fmaf(bi, W1[mm * 67 + 66], b1[mm]);
}

// ---------------------------------------------------------------------------
// k_main: m[j][:] += sum_i relu(W3 @ relu(W2 @ relu(u_i + v_j + J_ij*wJ) + b2) + b3)
// grid 512 blocks x 256 threads.
//   block: jb = blockIdx & 31 (32 j's), cb = blockIdx >> 5 (16 chunk-groups)
//   thread: jj = tid & 31, cc = tid >> 5 ; i0 = (cb*8+cc)*8, 8 i's per thread
// ---------------------------------------------------------------------------
__global__ __launch_bounds__(256) void k_main(
    const float* __restrict__ J,  const float* __restrict__ W1,
    const float* __restrict__ W2, const float* __restrict__ b2,
    const float* __restrict__ W3, const float* __restrict__ b3,
    const float* __restrict__ u,  const float* __restrict__ v,
    float* __restrict__ mout)
{
    __shared__ float red[256 * 33];   // stride-33 padding: conflict-free
    const int tid = threadIdx.x;
    const int jj = tid & 31;
    const int cc = tid >> 5;
    const int jb = blockIdx.x & 31;
    const int cb = blockIdx.x >> 5;
    const int j  = jb * 32 + jj;
    const int i0 = (cb * 8 + cc) * 8;

    // wave-uniform weights -> s_load expected
    float wj[32];
#pragma unroll
    for (int m = 0; m < 32; m++) wj[m] = W1[m * 67 + 64];

    float vv[32];
#pragma unroll
    for (int m = 0; m < 32; m += 4) {
        float4 t4 = *(const float4*)(v + j * 32 + m);
        vv[m] = t4.x; vv[m + 1] = t4.y; vv[m + 2] = t4.z; vv[m + 3] = t4.w;
    }

    float acc[32];
#pragma unroll
    for (int m = 0; m < 32; m++) acc[m] = 0.0f;

#pragma unroll 1
    for (int it = 0; it < 8; ++it) {
        const int i = i0 + it;
        const float Jw = J[i * NN + j];

        float x[32];
#pragma unroll
        for (int mq = 0; mq < 8; mq++) {
            float4 uu = *(const float4*)(u + i * 32 + 4 * mq);
            x[4 * mq + 0] = fmaxf(0.0f, fmaf(Jw, wj[4 * mq + 0], uu.x + vv[4 * mq + 0]));
            x[4 * mq + 1] = fmaxf(0.0f, fmaf(Jw, wj[4 * mq + 1], uu.y + vv[4 * mq + 1]));
            x[4 * mq + 2] = fmaxf(0.0f, fmaf(Jw, wj[4 * mq + 2], uu.z + vv[4 * mq + 2]));
            x[4 * mq + 3] = fmaxf(0.0f, fmaf(Jw, wj[4 * mq + 3], uu.w + vv[4 * mq + 3]));
        }

        float y[32];
#pragma unroll
        for (int m = 0; m < 32; m++) {
            float t = b2[m];
#pragma unroll
            for (int k = 0; k < 32; k++) t = fmaf(W2[m * 32 + k], x[k], t);
            y[m] = fmaxf(t, 0.0f);
        }

#pragma unroll
        for (int m = 0; m < 32; m++) {
            float t = b3[m];
#pragma unroll
            for (int k = 0; k < 32; k++) t = fmaf(W3[m * 32 + k], y[k], t);
            acc[m] += fmaxf(t, 0.0f);
        }
    }

    // LDS reduction over the 8 cc-groups, then one atomic per (j, m) per block
#pragma unroll
    for (int m = 0; m < 32; m++) red[tid * 33 + m] = acc[m];
    __syncthreads();

#pragma unroll
    for (int q = 0; q < 4; q++) {
        int cell = tid * 4 + q;          // 0..1023
        int jj2 = cell >> 5;
        int m2  = cell & 31;
        float s = 0.0f;
#pragma unroll
        for (int c2 = 0; c2 < 8; c2++) s += red[(c2 * 32 + jj2) * 33 + m2];
        unsafeAtomicAdd(&mout[(jb * 32 + jj2) * 32 + m2], s);
    }
}

// ---------------------------------------------------------------------------
// k_gru: per row j (32 lanes per row, 8 rows per 256-block, 128 blocks)
//   gi = [h;m] @ W_ih^T + b_ih ; gates ; h_new = (1-z)*n
//   then refresh u[j], v[j] from h_new, zero m[j] for next step
// ---------------------------------------------------------------------------
__global__ __launch_bounds__(256) void k_gru(
    const float* __restrict__ Wih, const float* __restrict__ bih,
    const float* __restrict__ bhh, const float* __restrict__ W1,
    const float* __restrict__ b,   const float* __restrict__ b1,
    float* __restrict__ h, float* __restrict__ mbuf,
    float* __restrict__ u, float* __restrict__ v)
{
    const int tid = threadIdx.x;
    const int s = tid & 31;
    const int j = blockIdx.x * 8 + (tid >> 5);

    const float hval = h[j * 32 + s];
    const float mval = mbuf[j * 32 + s];
    mbuf[j * 32 + s] = 0.0f;   // ready for next step's atomics

    float g0 = bih[s];
    float g1 = bih[32 + s];
    float g2 = bih[64 + s];
#pragma unroll
    for (int k = 0; k < 32; k++) {
        float hk = __shfl(hval, k, 32);
        float mk = __shfl(mval, k, 32);
        g0 = fmaf(Wih[s * 64 + k],        hk, g0);
        g0 = fmaf(Wih[s * 64 + 32 + k],   mk, g0);
        g1 = fmaf(Wih[(32 + s) * 64 + k],      hk, g1);
        g1 = fmaf(Wih[(32 + s) * 64 + 32 + k], mk, g1);
        g2 = fmaf(Wih[(64 + s) * 64 + k],      hk, g2);
        g2 = fmaf(Wih[(64 + s) * 64 + 32 + k], mk, g2);
    }
    float r = sigmoidf_(g0 + bhh[s]);
    float z = sigmoidf_(g1 + bhh[32 + s]);
    float n = tanhf(g2 + r * bhh[64 + s]);
    float hn = (1.0f - z) * n;
    h[j * 32 + s] = hn;

    // u[j][s] = sum_k W1a[s][k]*hn[k] + b[j]*wbi[s]
    // v[j][s] = sum_k W1b[s][k]*hn[k] + b[j]*wbj[s] + b1[s]
    float bj = b[j];
    float uacc = bj * W1[s * 67 + 65];
    float vacc = fmaf(bj, W1[s * 67 + 66], b1[s]);
#pragma unroll
    for (int k = 0; k < 32; k++) {
        float hk = __shfl(hn, k, 32);
        uacc = fmaf(W1[s * 67 + k],      hk, uacc);
        vacc = fmaf(W1[s * 67 + 32 + k], hk, vacc);
    }
    u[j * 32 + s] = uacc;
    v[j * 32 + s] = vacc;
}

// ---------------------------------------------------------------------------
// k_out: readout.  32 lanes per row j; lanes 0,1 write out[j*2 + {0,1}]
// ---------------------------------------------------------------------------
__global__ __launch_bounds__(256) void k_out(
    const float* __restrict__ h,
    const float* __restrict__ R1, const float* __restrict__ rb1,
    const float* __restrict__ R2, const float* __restrict__ rb2,
    const float* __restrict__ R3, const float* __restrict__ rb3,
    float* __restrict__ out)
{
    const int tid = threadIdx.x;
    const int s = tid & 31;
    const int j = blockIdx.x * 8 + (tid >> 5);

    float hv = h[j * 32 + s];
    float a1 = rb1[s];
#pragma unroll
    for (int k = 0; k < 32; k++) a1 = fmaf(R1[s * 32 + k], __shfl(hv, k, 32), a1);
    a1 = fmaxf(a1, 0.0f);

    float a2 = rb2[s];
#pragma unroll
    for (int k = 0; k < 32; k++) a2 = fmaf(R2[s * 32 + k], __shfl(a1, k, 32), a2);
    a2 = fmaxf(a2, 0.0f);

    float acc3 = 0.0f;
#pragma unroll
    for (int k = 0; k < 32; k++) {
        float a2k = __shfl(a2, k, 32);
        if (s < 2) acc3 = fmaf(R3[s * 32 + k], a2k, acc3);
    }
    if (s < 2) {
        float r3 = fmaxf(acc3 + rb3[s], 0.0f);
        out[j * 2 + s] = sigmoidf_(r3);
    }
}

// ---------------------------------------------------------------------------
extern "C" void kernel_launch(void* const* d_in, const int* in_sizes, int n_in,
                              void* d_out, int out_size, void* d_ws, size_t ws_size,
                              hipStream_t stream)
{
    const float* J   = (const float*)d_in[0];
    const float* b   = (const float*)d_in[1];
    const float* W1  = (const float*)d_in[2];
    const float* b1  = (const float*)d_in[3];
    const float* W2  = (const float*)d_in[4];
    const float* b2  = (const float*)d_in[5];
    const float* W3  = (const float*)d_in[6];
    const float* b3  = (const float*)d_in[7];
    const float* Wih = (const float*)d_in[8];
    const float* bih = (const float*)d_in[9];
    const float* bhh = (const float*)d_in[10];
    const float* R1  = (const float*)d_in[11];
    const float* rb1 = (const float*)d_in[12];
    const float* R2  = (const float*)d_in[13];
    const float* rb2 = (const float*)d_in[14];
    const float* R3  = (const float*)d_in[15];
    const float* rb3 = (const float*)d_in[16];

    float* out = (float*)d_out;
    float* ws  = (float*)d_ws;
    float* h  = ws;
    float* mb = ws + 32768;
    float* u  = ws + 65536;
    float* v  = ws + 98304;

    k_init<<<128, 256, 0, stream>>>(b, W1, b1, h, mb, u, v);
    for (int step = 0; step < 5; ++step) {
        k_main<<<512, 256, 0, stream>>>(J, W1, W2, b2, W3, b3, u, v, mb);
        k_gru<<<128, 256, 0, stream>>>(Wih, bih, bhh, W1, b, b1, h, mb, u, v);
    }
    k_out<<<128, 256, 0, stream>>>(h, R1, rb1, R2, rb2, R3, rb3, out);
}

// Round 2
// 247.124 us; speedup vs baseline: 20.9649x; 20.9649x over previous
//
#include <hip/hip_runtime.h>
#include <hip/hip_bf16.h>
#include <math.h>

#define NN 1024

typedef __attribute__((ext_vector_type(8))) short bf16x8;
typedef __attribute__((ext_vector_type(4))) float f32x4;
typedef __attribute__((ext_vector_type(4))) unsigned int u32x4;

__device__ __forceinline__ float sigmoidf_(float x) { return 1.0f / (1.0f + __expf(-x)); }

__device__ __forceinline__ unsigned short f2bf(float x) {
    __hip_bfloat16 h = __float2bfloat16(x);
    return *reinterpret_cast<unsigned short*>(&h);
}
__device__ __forceinline__ unsigned int pack2(unsigned short a, unsigned short b) {
    return (unsigned int)a | ((unsigned int)b << 16);
}

// ---------------------------------------------------------------------------
// k_init: h=0, m=0, u[i][mm]=b[i]*wbi[mm], v[j][mm]=b[j]*wbj[mm]+b1[mm]
// ---------------------------------------------------------------------------
__global__ __launch_bounds__(256) void k_init(
    const float* __restrict__ b, const float* __restrict__ W1,
    const float* __restrict__ b1, float* __restrict__ h,
    float* __restrict__ mbuf, float* __restrict__ u, float* __restrict__ v)
{
    int t = blockIdx.x * 256 + threadIdx.x;   // 0..32767
    int row = t >> 5;
    int mm  = t & 31;
    float bi = b[row];
    h[t]    = 0.0f;
    mbuf[t] = 0.0f;
    u[t] = bi * W1[mm * 67 + 65];
    v[t] = fmaf(bi, W1[mm * 67 + 66], b1[mm]);
}

// ---------------------------------------------------------------------------
// k_tr: Jt[j][i] = J[i][j]
// ---------------------------------------------------------------------------
__global__ __launch_bounds__(256) void k_tr(
    const float* __restrict__ J, float* __restrict__ Jt)
{
    __shared__ float tile[32][33];
    int bx = blockIdx.x * 32, by = blockIdx.y * 32;
    int x = threadIdx.x, y = threadIdx.y;   // 32 x 8
#pragma unroll
    for (int r = 0; r < 4; r++)
        tile[y + 8 * r][x] = J[(by + y + 8 * r) * NN + bx + x];
    __syncthreads();
#pragma unroll
    for (int r = 0; r < 4; r++)
        Jt[(bx + y + 8 * r) * NN + by + x] = tile[x][y + 8 * r];
}

// ---------------------------------------------------------------------------
// k_main (MFMA): one block per j. 4 waves, each covers 256 i's in 16-pair tiles.
//   GEMM2: D2[f][p] = sum_k W2[f][k] * X[p][k]   (A=W2 frag, B=X frag)
//   Y = relu(D2 + b2) -> LDS relayout (C-layout -> B-layout), bf16
//   GEMM3: D3[f'][p] = sum_f W3[f'][f] * Y[f][p]
//   acc += relu(D3 + b3); reduce over p (shfl) + waves (LDS); store m[j].
// ---------------------------------------------------------------------------
__global__ __launch_bounds__(256) void k_main(
    const float* __restrict__ J, const float* __restrict__ Jt, int useJt,
    const float* __restrict__ W1,
    const float* __restrict__ W2, const float* __restrict__ b2,
    const float* __restrict__ W3, const float* __restrict__ b3,
    const float* __restrict__ u,  const float* __restrict__ v,
    float* __restrict__ mout)
{
    __shared__ unsigned int ybuf[4 * 640];   // per wave: 2 x 320 dwords (double buffer)
    __shared__ float red[4 * 32];

    const int tid = threadIdx.x;
    const int w = tid >> 6;
    const int l = tid & 63;
    const int p = l & 15;        // pair-in-tile / B-frag column
    const int q = l >> 4;        // quad: k-chunk index
    const int j = blockIdx.x;

    // --- preload W2/W3 A-frags as bf16: A[m=p][k=q*8+jj] ---
    union FU { bf16x8 v; unsigned short s[8]; } w2a0, w2a1, w3a0, w3a1;
#pragma unroll
    for (int jj = 0; jj < 8; jj++) {
        int k = q * 8 + jj;
        w2a0.s[jj] = f2bf(W2[p * 32 + k]);
        w2a1.s[jj] = f2bf(W2[(16 + p) * 32 + k]);
        w3a0.s[jj] = f2bf(W3[p * 32 + k]);
        w3a1.s[jj] = f2bf(W3[(16 + p) * 32 + k]);
    }
    // --- per-lane constants: v[j][k-range], wJ[k-range], biases per C-row ---
    float vv[8], wj8[8];
#pragma unroll
    for (int jj = 0; jj < 8; jj++) {
        int k = q * 8 + jj;
        vv[jj]  = v[j * 32 + k];
        wj8[jj] = W1[k * 67 + 64];
    }
    float b2v0[4], b2v1[4], b3v0[4], b3v1[4];
#pragma unroll
    for (int r = 0; r < 4; r++) {
        b2v0[r] = b2[q * 4 + r];  b2v1[r] = b2[16 + q * 4 + r];
        b3v0[r] = b3[q * 4 + r];  b3v1[r] = b3[16 + q * 4 + r];
    }

    const f32x4 zero = {0.f, 0.f, 0.f, 0.f};
    f32x4 acc0 = zero, acc1 = zero;

    const float* __restrict__ jptr = useJt ? (Jt + (size_t)j * NN) : (J + j);
    const int jstride = useJt ? 1 : NN;
    const int ibase = w * 256;

#pragma unroll 2
    for (int t = 0; t < 16; ++t) {
        const int i = ibase + t * 16 + p;
        const float jw = jptr[(size_t)i * jstride];
        const float4 u0 = *(const float4*)(u + i * 32 + q * 8);
        const float4 u1 = *(const float4*)(u + i * 32 + q * 8 + 4);
        float xk[8];
        xk[0] = u0.x; xk[1] = u0.y; xk[2] = u0.z; xk[3] = u0.w;
        xk[4] = u1.x; xk[5] = u1.y; xk[6] = u1.z; xk[7] = u1.w;

        union FU bx;
#pragma unroll
        for (int jj = 0; jj < 8; jj++) {
            float t2 = fmaf(jw, wj8[jj], xk[jj] + vv[jj]);
            bx.s[jj] = f2bf(fmaxf(t2, 0.f));
        }

        f32x4 c0 = __builtin_amdgcn_mfma_f32_16x16x32_bf16(w2a0.v, bx.v, zero, 0, 0, 0);
        f32x4 c1 = __builtin_amdgcn_mfma_f32_16x16x32_bf16(w2a1.v, bx.v, zero, 0, 0, 0);

        // Y = relu(D2 + b2) -> LDS, layout Y[p][f] bf16, row stride 80 B
        unsigned int* yb = ybuf + w * 640 + (t & 1) * 320;
        unsigned int d0 = pack2(f2bf(fmaxf(c0[0] + b2v0[0], 0.f)),
                                f2bf(fmaxf(c0[1] + b2v0[1], 0.f)));
        unsigned int d1 = pack2(f2bf(fmaxf(c0[2] + b2v0[2], 0.f)),
                                f2bf(fmaxf(c0[3] + b2v0[3], 0.f)));
        unsigned int d2 = pack2(f2bf(fmaxf(c1[0] + b2v1[0], 0.f)),
                                f2bf(fmaxf(c1[1] + b2v1[1], 0.f)));
        unsigned int d3 = pack2(f2bf(fmaxf(c1[2] + b2v1[2], 0.f)),
                                f2bf(fmaxf(c1[3] + b2v1[3], 0.f)));
        yb[p * 20 + q * 2 + 0] = d0;       // f = 4q..4q+1
        yb[p * 20 + q * 2 + 1] = d1;       // f = 4q+2..4q+3
        yb[p * 20 + 8 + q * 2 + 0] = d2;   // f = 16+4q..
        yb[p * 20 + 8 + q * 2 + 1] = d3;

        // B-frag for GEMM3: lane needs Y[f=q*8+jj][p] -> 16 contiguous bytes
        union { u32x4 u4; bf16x8 v; } yrd;
        yrd.u4 = *(const u32x4*)(yb + p * 20 + q * 4);

        f32x4 e0 = __builtin_amdgcn_mfma_f32_16x16x32_bf16(w3a0.v, yrd.v, zero, 0, 0, 0);
        f32x4 e1 = __builtin_amdgcn_mfma_f32_16x16x32_bf16(w3a1.v, yrd.v, zero, 0, 0, 0);
#pragma unroll
        for (int r = 0; r < 4; r++) {
            acc0[r] += fmaxf(e0[r] + b3v0[r], 0.f);
            acc1[r] += fmaxf(e1[r] + b3v1[r], 0.f);
        }
    }

    // reduce over p (bits 0..3 of lane id)
#pragma unroll
    for (int bit = 1; bit < 16; bit <<= 1) {
#pragma unroll
        for (int r = 0; r < 4; r++) {
            acc0[r] += __shfl_xor(acc0[r], bit);
            acc1[r] += __shfl_xor(acc1[r], bit);
        }
    }
    if (p == 0) {
#pragma unroll
        for (int r = 0; r < 4; r++) {
            red[w * 32 + q * 4 + r]      = acc0[r];
            red[w * 32 + 16 + q * 4 + r] = acc1[r];
        }
    }
    __syncthreads();
    if (tid < 32) {
        float s = red[tid] + red[32 + tid] + red[64 + tid] + red[96 + tid];
        mout[j * 32 + tid] = s;
    }
}

// ---------------------------------------------------------------------------
// k_gru: per row j (32 lanes per row, 8 rows per 256-block, 128 blocks)
// ---------------------------------------------------------------------------
__global__ __launch_bounds__(256) void k_gru(
    const float* __restrict__ Wih, const float* __restrict__ bih,
    const float* __restrict__ bhh, const float* __restrict__ W1,
    const float* __restrict__ b,   const float* __restrict__ b1,
    float* __restrict__ h, float* __restrict__ mbuf,
    float* __restrict__ u, float* __restrict__ v)
{
    const int tid = threadIdx.x;
    const int s = tid & 31;
    const int j = blockIdx.x * 8 + (tid >> 5);

    const float hval = h[j * 32 + s];
    const float mval = mbuf[j * 32 + s];

    float g0 = bih[s];
    float g1 = bih[32 + s];
    float g2 = bih[64 + s];
#pragma unroll
    for (int k = 0; k < 32; k++) {
        float hk = __shfl(hval, k, 32);
        float mk = __shfl(mval, k, 32);
        g0 = fmaf(Wih[s * 64 + k],        hk, g0);
        g0 = fmaf(Wih[s * 64 + 32 + k],   mk, g0);
        g1 = fmaf(Wih[(32 + s) * 64 + k],      hk, g1);
        g1 = fmaf(Wih[(32 + s) * 64 + 32 + k], mk, g1);
        g2 = fmaf(Wih[(64 + s) * 64 + k],      hk, g2);
        g2 = fmaf(Wih[(64 + s) * 64 + 32 + k], mk, g2);
    }
    float r = sigmoidf_(g0 + bhh[s]);
    float z = sigmoidf_(g1 + bhh[32 + s]);
    float n = tanhf(g2 + r * bhh[64 + s]);
    float hn = (1.0f - z) * n;
    h[j * 32 + s] = hn;

    float bj = b[j];
    float uacc = bj * W1[s * 67 + 65];
    float vacc = fmaf(bj, W1[s * 67 + 66], b1[s]);
#pragma unroll
    for (int k = 0; k < 32; k++) {
        float hk = __shfl(hn, k, 32);
        uacc = fmaf(W1[s * 67 + k],      hk, uacc);
        vacc = fmaf(W1[s * 67 + 32 + k], hk, vacc);
    }
    u[j * 32 + s] = uacc;
    v[j * 32 + s] = vacc;
}

// ---------------------------------------------------------------------------
// k_out: readout
// ---------------------------------------------------------------------------
__global__ __launch_bounds__(256) void k_out(
    const float* __restrict__ h,
    const float* __restrict__ R1, const float* __restrict__ rb1,
    const float* __restrict__ R2, const float* __restrict__ rb2,
    const float* __restrict__ R3, const float* __restrict__ rb3,
    float* __restrict__ out)
{
    const int tid = threadIdx.x;
    const int s = tid & 31;
    const int j = blockIdx.x * 8 + (tid >> 5);

    float hv = h[j * 32 + s];
    float a1 = rb1[s];
#pragma unroll
    for (int k = 0; k < 32; k++) a1 = fmaf(R1[s * 32 + k], __shfl(hv, k, 32), a1);
    a1 = fmaxf(a1, 0.0f);

    float a2 = rb2[s];
#pragma unroll
    for (int k = 0; k < 32; k++) a2 = fmaf(R2[s * 32 + k], __shfl(a1, k, 32), a2);
    a2 = fmaxf(a2, 0.0f);

    float acc3 = 0.0f;
#pragma unroll
    for (int k = 0; k < 32; k++) {
        float a2k = __shfl(a2, k, 32);
        if (s < 2) acc3 = fmaf(R3[s * 32 + k], a2k, acc3);
    }
    if (s < 2) {
        float r3 = fmaxf(acc3 + rb3[s], 0.0f);
        out[j * 2 + s] = sigmoidf_(r3);
    }
}

// ---------------------------------------------------------------------------
extern "C" void kernel_launch(void* const* d_in, const int* in_sizes, int n_in,
                              void* d_out, int out_size, void* d_ws, size_t ws_size,
                              hipStream_t stream)
{
    const float* J   = (const float*)d_in[0];
    const float* b   = (const float*)d_in[1];
    const float* W1  = (const float*)d_in[2];
    const float* b1  = (const float*)d_in[3];
    const float* W2  = (const float*)d_in[4];
    const float* b2  = (const float*)d_in[5];
    const float* W3  = (const float*)d_in[6];
    const float* b3  = (const float*)d_in[7];
    const float* Wih = (const float*)d_in[8];
    const float* bih = (const float*)d_in[9];
    const float* bhh = (const float*)d_in[10];
    const float* R1  = (const float*)d_in[11];
    const float* rb1 = (const float*)d_in[12];
    const float* R2  = (const float*)d_in[13];
    const float* rb2 = (const float*)d_in[14];
    const float* R3  = (const float*)d_in[15];
    const float* rb3 = (const float*)d_in[16];

    float* out = (float*)d_out;
    float* ws  = (float*)d_ws;
    float* h  = ws;
    float* mb = ws + 32768;
    float* u  = ws + 65536;
    float* v  = ws + 98304;
    float* Jt = ws + 131072;

    const size_t need = (131072 + (size_t)NN * NN) * sizeof(float);
    const int useJt = (ws_size >= need) ? 1 : 0;

    k_init<<<128, 256, 0, stream>>>(b, W1, b1, h, mb, u, v);
    if (useJt) k_tr<<<dim3(32, 32), dim3(32, 8), 0, stream>>>(J, Jt);
    for (int step = 0; step < 5; ++step) {
        k_main<<<1024, 256, 0, stream>>>(J, Jt, useJt, W1, W2, b2, W3, b3, u, v, mb);
        k_gru<<<128, 256, 0, stream>>>(Wih, bih, bhh, W1, b, b1, h, mb, u, v);
    }
    k_out<<<128, 256, 0, stream>>>(h, R1, rb1, R2, rb2, R3, rb3, out);
}

// Round 4
// 224.511 us; speedup vs baseline: 23.0765x; 1.1007x over previous
//
#include <hip/hip_runtime.h>
#include <hip/hip_cooperative_groups.h>
#include <math.h>

namespace cg = cooperative_groups;

#define NN 1024

typedef __attribute__((ext_vector_type(8))) short bf16x8;
typedef __attribute__((ext_vector_type(4))) float f32x4;
typedef __attribute__((ext_vector_type(4))) unsigned int u32x4;

__device__ __forceinline__ float sigmoidf_(float x) { return 1.0f / (1.0f + __expf(-x)); }

// RNE bf16 round; pack two floats into one dword (lo = a, hi = b)
__device__ __forceinline__ unsigned int pk_bf16(float a, float b) {
    unsigned int ua = __float_as_uint(a), ub = __float_as_uint(b);
    ua += 0x7fffu + ((ua >> 16) & 1u);
    ub += 0x7fffu + ((ub >> 16) & 1u);
    return (ua >> 16) | (ub & 0xffff0000u);
}
__device__ __forceinline__ unsigned short f2bf_rne(float a) {
    unsigned int ua = __float_as_uint(a);
    ua += 0x7fffu + ((ua >> 16) & 1u);
    return (unsigned short)(ua >> 16);
}

// ---------------------------------------------------------------------------
// Per-lane persistent MFMA context
// ---------------------------------------------------------------------------
struct Ctx {
    bf16x8 w2a0, w2a1, w3a0, w3a1;
    f32x4 b2v0, b2v1, b3v0, b3v1;   // biases folded into MFMA C operand
    float wj8[8];
};

__device__ __forceinline__ void make_ctx(Ctx& c, int p, int q,
    const float* __restrict__ W1, const float* __restrict__ W2,
    const float* __restrict__ b2, const float* __restrict__ W3,
    const float* __restrict__ b3)
{
    union FU { bf16x8 v; unsigned short s[8]; } t0, t1, t2, t3;
#pragma unroll
    for (int jj = 0; jj < 8; jj++) {
        int k = q * 8 + jj;
        t0.s[jj] = f2bf_rne(W2[p * 32 + k]);
        t1.s[jj] = f2bf_rne(W2[(16 + p) * 32 + k]);
        t2.s[jj] = f2bf_rne(W3[p * 32 + k]);
        t3.s[jj] = f2bf_rne(W3[(16 + p) * 32 + k]);
        c.wj8[jj] = W1[k * 67 + 64];
    }
    c.w2a0 = t0.v; c.w2a1 = t1.v; c.w3a0 = t2.v; c.w3a1 = t3.v;
#pragma unroll
    for (int r = 0; r < 4; r++) {
        c.b2v0[r] = b2[q * 4 + r];  c.b2v1[r] = b2[16 + q * 4 + r];
        c.b3v0[r] = b3[q * 4 + r];  c.b3v1[r] = b3[16 + q * 4 + r];
    }
}

// One 16-pair tile: X build -> MFMA W2 (+b2 in C) -> relu -> LDS relayout ->
// MFMA W3 (+b3 in C) -> relu -> fp32 accumulate
__device__ __forceinline__ void tile_op(const Ctx& c,
    const float* __restrict__ Jtrow, const float* __restrict__ u,
    const float* vv, unsigned int* yb, int i, int p, int q,
    f32x4& acc0, f32x4& acc1)
{
    const float jw = Jtrow[i];
    const float4 u0 = *(const float4*)(u + i * 32 + q * 8);
    const float4 u1 = *(const float4*)(u + i * 32 + q * 8 + 4);
    float xr[8];
    xr[0] = fmaxf(fmaf(jw, c.wj8[0], u0.x + vv[0]), 0.f);
    xr[1] = fmaxf(fmaf(jw, c.wj8[1], u0.y + vv[1]), 0.f);
    xr[2] = fmaxf(fmaf(jw, c.wj8[2], u0.z + vv[2]), 0.f);
    xr[3] = fmaxf(fmaf(jw, c.wj8[3], u0.w + vv[3]), 0.f);
    xr[4] = fmaxf(fmaf(jw, c.wj8[4], u1.x + vv[4]), 0.f);
    xr[5] = fmaxf(fmaf(jw, c.wj8[5], u1.y + vv[5]), 0.f);
    xr[6] = fmaxf(fmaf(jw, c.wj8[6], u1.z + vv[6]), 0.f);
    xr[7] = fmaxf(fmaf(jw, c.wj8[7], u1.w + vv[7]), 0.f);

    union BU { u32x4 u4; bf16x8 v; unsigned int d[4]; } bx;
#pragma unroll
    for (int cc = 0; cc < 4; cc++) bx.d[cc] = pk_bf16(xr[2 * cc], xr[2 * cc + 1]);

    f32x4 c0 = __builtin_amdgcn_mfma_f32_16x16x32_bf16(c.w2a0, bx.v, c.b2v0, 0, 0, 0);
    f32x4 c1 = __builtin_amdgcn_mfma_f32_16x16x32_bf16(c.w2a1, bx.v, c.b2v1, 0, 0, 0);

    yb[p * 20 + q * 2 + 0]     = pk_bf16(fmaxf(c0[0], 0.f), fmaxf(c0[1], 0.f));
    yb[p * 20 + q * 2 + 1]     = pk_bf16(fmaxf(c0[2], 0.f), fmaxf(c0[3], 0.f));
    yb[p * 20 + 8 + q * 2 + 0] = pk_bf16(fmaxf(c1[0], 0.f), fmaxf(c1[1], 0.f));
    yb[p * 20 + 8 + q * 2 + 1] = pk_bf16(fmaxf(c1[2], 0.f), fmaxf(c1[3], 0.f));

    union BU yrd;
    yrd.u4 = *(const u32x4*)(yb + p * 20 + q * 4);

    f32x4 e0 = __builtin_amdgcn_mfma_f32_16x16x32_bf16(c.w3a0, yrd.v, c.b3v0, 0, 0, 0);
    f32x4 e1 = __builtin_amdgcn_mfma_f32_16x16x32_bf16(c.w3a1, yrd.v, c.b3v1, 0, 0, 0);
#pragma unroll
    for (int r = 0; r < 4; r++) {
        acc0[r] += fmaxf(e0[r], 0.f);
        acc1[r] += fmaxf(e1[r], 0.f);
    }
}

__device__ __forceinline__ void gru_row(int s, float hval, float mval, float bj,
    const float* __restrict__ Wih, const float* __restrict__ bih,
    const float* __restrict__ bhh, const float* __restrict__ W1,
    const float* __restrict__ b1, float& hn, float& uacc, float& vacc)
{
    float g0 = bih[s], g1 = bih[32 + s], g2 = bih[64 + s];
#pragma unroll 8
    for (int k = 0; k < 32; k++) {
        float hk = __shfl(hval, k, 32);
        float mk = __shfl(mval, k, 32);
        g0 = fmaf(Wih[s * 64 + k],             hk, g0);
        g0 = fmaf(Wih[s * 64 + 32 + k],        mk, g0);
        g1 = fmaf(Wih[(32 + s) * 64 + k],      hk, g1);
        g1 = fmaf(Wih[(32 + s) * 64 + 32 + k], mk, g1);
        g2 = fmaf(Wih[(64 + s) * 64 + k],      hk, g2);
        g2 = fmaf(Wih[(64 + s) * 64 + 32 + k], mk, g2);
    }
    float r = sigmoidf_(g0 + bhh[s]);
    float z = sigmoidf_(g1 + bhh[32 + s]);
    float n = tanhf(g2 + r * bhh[64 + s]);
    hn = (1.0f - z) * n;
    float ua = bj * W1[s * 67 + 65];
    float va = fmaf(bj, W1[s * 67 + 66], b1[s]);
#pragma unroll 8
    for (int k = 0; k < 32; k++) {
        float hk = __shfl(hn, k, 32);
        ua = fmaf(W1[s * 67 + k],      hk, ua);
        va = fmaf(W1[s * 67 + 32 + k], hk, va);
    }
    uacc = ua; vacc = va;
}

__device__ __forceinline__ void readout_row(int s, int j, float hn,
    const float* __restrict__ R1, const float* __restrict__ rb1,
    const float* __restrict__ R2, const float* __restrict__ rb2,
    const float* __restrict__ R3, const float* __restrict__ rb3,
    float* __restrict__ out)
{
    float a1 = rb1[s];
#pragma unroll 8
    for (int k = 0; k < 32; k++) a1 = fmaf(R1[s * 32 + k], __shfl(hn, k, 32), a1);
    a1 = fmaxf(a1, 0.f);
    float a2 = rb2[s];
#pragma unroll 8
    for (int k = 0; k < 32; k++) a2 = fmaf(R2[s * 32 + k], __shfl(a1, k, 32), a2);
    a2 = fmaxf(a2, 0.f);
    float a3 = (s < 2) ? rb3[s] : 0.f;
#pragma unroll 8
    for (int k = 0; k < 32; k++) {
        float a2k = __shfl(a2, k, 32);
        if (s < 2) a3 = fmaf(R3[s * 32 + k], a2k, a3);
    }
    if (s < 2) out[j * 2 + s] = sigmoidf_(fmaxf(a3, 0.f));
}

// ---------------------------------------------------------------------------
// k_pre: blocks 0..1023 transpose J -> Jt; blocks 1024..1151 init h, u0, v
// ---------------------------------------------------------------------------
__global__ __launch_bounds__(256) void k_pre(
    const float* __restrict__ J, const float* __restrict__ b,
    const float* __restrict__ W1, const float* __restrict__ b1,
    float* __restrict__ Jt, float* __restrict__ h,
    float* __restrict__ u0, float* __restrict__ v)
{
    __shared__ float tile[32][33];
    const int t = blockIdx.x;
    const int tid = threadIdx.x;
    if (t < 1024) {
        int tx = (t & 31) * 32, ty = (t >> 5) * 32;
        int x = tid & 31, y = tid >> 5;   // y in 0..7
#pragma unroll
        for (int r = 0; r < 4; r++)
            tile[y + 8 * r][x] = J[(size_t)(ty + y + 8 * r) * NN + tx + x];
        __syncthreads();
#pragma unroll
        for (int r = 0; r < 4; r++)
            Jt[(size_t)(tx + y + 8 * r) * NN + ty + x] = tile[x][y + 8 * r];
    } else {
        int idx = (t - 1024) * 256 + tid;   // 0..32767
        int row = idx >> 5, mm = idx & 31;
        float bi = b[row];
        h[idx]  = 0.f;
        u0[idx] = bi * W1[mm * 67 + 65];
        v[idx]  = fmaf(bi, W1[mm * 67 + 66], b1[mm]);
    }
}

// ---------------------------------------------------------------------------
// k_coop: persistent, 1024 blocks x 128 threads (2 waves). Needs only
// 4 blocks/CU = 2 waves/EU -> <=256 VGPR budget, cannot miss co-residency.
// ---------------------------------------------------------------------------
__global__ __launch_bounds__(128, 2) void k_coop(
    const float* __restrict__ Jt, const float* __restrict__ W1,
    const float* __restrict__ W2, const float* __restrict__ b2,
    const float* __restrict__ W3, const float* __restrict__ b3,
    const float* __restrict__ Wih, const float* __restrict__ bih,
    const float* __restrict__ bhh, const float* __restrict__ b,
    const float* __restrict__ b1,
    const float* __restrict__ R1, const float* __restrict__ rb1,
    const float* __restrict__ R2, const float* __restrict__ rb2,
    const float* __restrict__ R3, const float* __restrict__ rb3,
    const float* __restrict__ vin, float* __restrict__ u0,
    float* __restrict__ u1, float* __restrict__ out)
{
    __shared__ unsigned int ybuf[2 * 4 * 320];   // 2 waves x quad buffer
    __shared__ float red[2 * 32];
    __shared__ float hbuf[32], vbuf[32];

    const int tid = threadIdx.x;
    const int w = tid >> 6;
    const int l = tid & 63;
    const int p = l & 15;
    const int q = l >> 4;
    const int j = blockIdx.x;

    Ctx c; make_ctx(c, p, q, W1, W2, b2, W3, b3);
    const float* Jtrow = Jt + (size_t)j * NN;

    if (tid < 32) { hbuf[tid] = 0.f; vbuf[tid] = vin[j * 32 + tid]; }
    __syncthreads();

    for (int step = 0; step < 5; ++step) {
        const float* ui = (step & 1) ? u1 : u0;
        float*       uo = (step & 1) ? u0 : u1;

        float vv[8];
#pragma unroll
        for (int jj = 0; jj < 8; jj++) vv[jj] = vbuf[q * 8 + jj];

        f32x4 acc0 = {0.f, 0.f, 0.f, 0.f}, acc1 = {0.f, 0.f, 0.f, 0.f};
#pragma unroll 4
        for (int t = 0; t < 32; ++t)
            tile_op(c, Jtrow, ui, vv, ybuf + w * 1280 + (t & 3) * 320,
                    w * 512 + t * 16 + p, p, q, acc0, acc1);

#pragma unroll
        for (int bit = 1; bit < 16; bit <<= 1) {
#pragma unroll
            for (int r = 0; r < 4; r++) {
                acc0[r] += __shfl_xor(acc0[r], bit);
                acc1[r] += __shfl_xor(acc1[r], bit);
            }
        }
        if (p == 0) {
#pragma unroll
            for (int r = 0; r < 4; r++) {
                red[w * 32 + q * 4 + r]      = acc0[r];
                red[w * 32 + 16 + q * 4 + r] = acc1[r];
            }
        }
        __syncthreads();

        if (tid < 32) {
            const int s = tid;
            float mval = red[s] + red[32 + s];
            float hn, ua, va;
            gru_row(s, hbuf[s], mval, b[j], Wih, bih, bhh, W1, b1, hn, ua, va);
            hbuf[s] = hn; vbuf[s] = va;
            uo[j * 32 + s] = ua;
            if (step == 4) readout_row(s, j, hn, R1, rb1, R2, rb2, R3, rb3, out);
        }
        if (step < 4) { __threadfence(); cg::this_grid().sync(); }
    }
}

// ---------------------------------------------------------------------------
// k_step (fallback): one step per launch, GRU fused in tail. u ping-pong.
// ---------------------------------------------------------------------------
__global__ __launch_bounds__(256, 4) void k_step(
    const float* __restrict__ Jt, const float* __restrict__ W1,
    const float* __restrict__ W2, const float* __restrict__ b2,
    const float* __restrict__ W3, const float* __restrict__ b3,
    const float* __restrict__ Wih, const float* __restrict__ bih,
    const float* __restrict__ bhh, const float* __restrict__ b,
    const float* __restrict__ b1,
    const float* __restrict__ R1, const float* __restrict__ rb1,
    const float* __restrict__ R2, const float* __restrict__ rb2,
    const float* __restrict__ R3, const float* __restrict__ rb3,
    float* __restrict__ h, float* __restrict__ v,
    const float* __restrict__ ui, float* __restrict__ uo,
    float* __restrict__ out, int do_out)
{
    __shared__ unsigned int ybuf[4 * 2 * 320];   // 4 waves x double buffer
    __shared__ float red[4 * 32];

    const int tid = threadIdx.x;
    const int w = tid >> 6;
    const int l = tid & 63;
    const int p = l & 15;
    const int q = l >> 4;
    const int j = blockIdx.x;

    Ctx c; make_ctx(c, p, q, W1, W2, b2, W3, b3);
    const float* Jtrow = Jt + (size_t)j * NN;

    float vv[8];
#pragma unroll
    for (int jj = 0; jj < 8; jj++) vv[jj] = v[j * 32 + q * 8 + jj];

    f32x4 acc0 = {0.f, 0.f, 0.f, 0.f}, acc1 = {0.f, 0.f, 0.f, 0.f};
#pragma unroll 2
    for (int t = 0; t < 16; ++t)
        tile_op(c, Jtrow, ui, vv, ybuf + w * 640 + (t & 1) * 320,
                w * 256 + t * 16 + p, p, q, acc0, acc1);

#pragma unroll
    for (int bit = 1; bit < 16; bit <<= 1) {
#pragma unroll
        for (int r = 0; r < 4; r++) {
            acc0[r] += __shfl_xor(acc0[r], bit);
            acc1[r] += __shfl_xor(acc1[r], bit);
        }
    }
    if (p == 0) {
#pragma unroll
        for (int r = 0; r < 4; r++) {
            red[w * 32 + q * 4 + r]      = acc0[r];
            red[w * 32 + 16 + q * 4 + r] = acc1[r];
        }
    }
    __syncthreads();

    if (tid < 32) {
        const int s = tid;
        float mval = red[s] + red[32 + s] + red[64 + s] + red[96 + s];
        float hn, ua, va;
        gru_row(s, h[j * 32 + s], mval, b[j], Wih, bih, bhh, W1, b1, hn, ua, va);
        h[j * 32 + s] = hn;
        v[j * 32 + s] = va;
        uo[j * 32 + s] = ua;
        if (do_out) readout_row(s, j, hn, R1, rb1, R2, rb2, R3, rb3, out);
    }
}

// ---------------------------------------------------------------------------
extern "C" void kernel_launch(void* const* d_in, const int* in_sizes, int n_in,
                              void* d_out, int out_size, void* d_ws, size_t ws_size,
                              hipStream_t stream)
{
    const float* J   = (const float*)d_in[0];
    const float* b   = (const float*)d_in[1];
    const float* W1  = (const float*)d_in[2];
    const float* b1  = (const float*)d_in[3];
    const float* W2  = (const float*)d_in[4];
    const float* b2  = (const float*)d_in[5];
    const float* W3  = (const float*)d_in[6];
    const float* b3  = (const float*)d_in[7];
    const float* Wih = (const float*)d_in[8];
    const float* bih = (const float*)d_in[9];
    const float* bhh = (const float*)d_in[10];
    const float* R1  = (const float*)d_in[11];
    const float* rb1 = (const float*)d_in[12];
    const float* R2  = (const float*)d_in[13];
    const float* rb2 = (const float*)d_in[14];
    const float* R3  = (const float*)d_in[15];
    const float* rb3 = (const float*)d_in[16];

    float* out = (float*)d_out;
    float* ws  = (float*)d_ws;
    float* h  = ws;
    float* v  = ws + 32768;
    float* u0 = ws + 65536;
    float* u1 = ws + 98304;
    float* Jt = ws + 131072;

    k_pre<<<1152, 256, 0, stream>>>(J, b, W1, b1, Jt, h, u0, v);

    // coop path: gate on the runtime's own occupancy calc (4 blocks/CU needed)
    int mb = 0;
    bool coop =
        (hipOccupancyMaxActiveBlocksPerMultiprocessor(
             &mb, reinterpret_cast<const void*>(&k_coop), 128, 0) == hipSuccess) &&
        (mb >= 4);
    if (coop) {
        const float* vin = v;
        void* cargs[] = { (void*)&Jt, (void*)&W1, (void*)&W2, (void*)&b2,
                          (void*)&W3, (void*)&b3, (void*)&Wih, (void*)&bih,
                          (void*)&bhh, (void*)&b, (void*)&b1,
                          (void*)&R1, (void*)&rb1, (void*)&R2, (void*)&rb2,
                          (void*)&R3, (void*)&rb3,
                          (void*)&vin, (void*)&u0, (void*)&u1, (void*)&out };
        if (hipLaunchCooperativeKernel(reinterpret_cast<const void*>(&k_coop),
                                       dim3(1024), dim3(128), cargs, 0, stream)
            != hipSuccess)
            coop = false;
    }
    if (!coop) {
        for (int s = 0; s < 5; s++) {
            const float* ui = (s & 1) ? u1 : u0;
            float*       uo = (s & 1) ? u0 : u1;
            k_step<<<1024, 256, 0, stream>>>(Jt, W1, W2, b2, W3, b3, Wih, bih,
                                             bhh, b, b1, R1, rb1, R2, rb2, R3,
                                             rb3, h, v, ui, uo, out,
                                             (s == 4) ? 1 : 0);
        }
    }
}